// Round 3
// baseline (66.106 us; speedup 1.0000x reference)
//
#include <hip/hip_runtime.h>

#ifndef __has_builtin
#define __has_builtin(x) 0
#endif

__device__ __forceinline__ float fast_exp2(float x) {
#if __has_builtin(__builtin_amdgcn_exp2f)
  return __builtin_amdgcn_exp2f(x);
#else
  return exp2f(x);
#endif
}
__device__ __forceinline__ float fast_rcp(float x) {
#if __has_builtin(__builtin_amdgcn_rcpf)
  return __builtin_amdgcn_rcpf(x);
#else
  return 1.0f / x;
#endif
}

#define NG     512
#define NSEG   8
#define SEGLEN 64          // gaussians per segment (one wave per segment)
#define PXB    128         // pixels per block = half an image row (constant y!)
#define QCUT   -21.0f      // exp2 exponent cutoff: alpha < 2^-21 ~ 4.8e-7 skipped

// ---------------- kernel 1: preprocess 512 gaussians once ----------------
// d_ws layout: A[NG] {mx,my,ka,kb} | B[NG] {kc,ko,-,-} | C[NG] {cr,cg,cb,-}
// exp2-space fold: alpha = exp2(ka*dx^2 + kb*dx*dy + kc*dy^2 + ko)
__global__ __launch_bounds__(NG, 1) void prep_kernel(
    const float* __restrict__ means, const float* __restrict__ cov,
    const float* __restrict__ opac,  const float* __restrict__ cols,
    float4* __restrict__ ws)
{
  const int g = threadIdx.x;
  const float mx = means[2*g], my = means[2*g+1];
  const float a = cov[4*g+0], b = cov[4*g+1], c = cov[4*g+2], d = cov[4*g+3];
  const float inv = 1.0f / (a*d - b*c);          // cov is PD, det >= 0.09
  const float HL2E = 0.72134752f;                // 0.5*log2(e)
  const float ka = -HL2E * d * inv;
  const float kb =  HL2E * (b + c) * inv;
  const float kc = -HL2E * a * inv;
  const float ko = log2f(opac[g]);               // opac in (0,1)
  ws[g]        = make_float4(mx, my, ka, kb);
  ws[NG + g]   = make_float4(kc, ko, 0.f, 0.f);
  ws[2*NG + g] = make_float4(cols[3*g+0], cols[3*g+1], cols[3*g+2], 0.f);
}

// ---------------- kernel 2: render ----------------
// Block: 512 threads = 8 waves. Wave s handles segment s (gaussians [64s,64s+64))
// for all 128 pixels of the block; lane l owns pixels (base+l) and (base+l+64).
// Segment partials (color accum + transmittance product) combine associatively
// in an LDS epilogue, preserving the reference's front-to-back cumprod order.
__global__ __launch_bounds__(512, 4) void render_kernel(
    const float4* __restrict__ ws, float* __restrict__ out)
{
  __shared__ float4 arrA[NG];          // 8 KB {mx,my,ka,kb}
  __shared__ float4 arrB[NG];          // 8 KB {kc,ko,-,-}
  __shared__ float4 colp[NG];          // 8 KB {cr,cg,cb,-}
  __shared__ float4 rowp[NG];          // 8 KB row-folded {mx,ka,B,cc} (built in cull)
  __shared__ float4 part[NSEG][PXB];   // 16 KB per-segment per-pixel partials
  __shared__ float  outstage[PXB * 3]; // 1.5 KB staged coalesced store

  const int tid = threadIdx.x;

  // ---- stage 24 KB of preprocessed params: 3 coalesced float4 per thread ----
  arrA[tid] = ws[tid];
  arrB[tid] = ws[NG + tid];
  colp[tid] = ws[2*NG + tid];
  __syncthreads();

  const int lane = tid & 63;
  const int seg  = tid >> 6;
  const int pixbase = blockIdx.x * PXB;
  const float py  = (float)(pixbase >> 8) + 0.5f;      // block-constant row
  const float x0f = (float)(pixbase & 255) + 0.5f;     // x of local pixel 0
  const float px0 = x0f + (float)lane;                 // lane's first pixel x

  // ---- per-wave cull + row-fold: lane l handles gaussian seg*64+l ----
  // q(dx) = ka*dx^2 + B*dx + cc is concave (ka<0): max at clamp(-B/(2ka), lo, hi).
  // Side effect: rowp[g] = {mx, ka, B, cc} for this block's row (same-wave RAW,
  // main loop of wave s reads only entries written by wave s -> no barrier).
  unsigned long long mask;
  {
    const int gt = seg * SEGLEN + lane;
    const float4 A  = arrA[gt];
    const float4 Bq = arrB[gt];
    const float dy = py - A.y;
    const float Bv = A.w * dy;                         // kb*dy
    const float cc = fmaf(Bq.x * dy, dy, Bq.y);        // kc*dy^2 + ko
    rowp[gt] = make_float4(A.x, A.z, Bv, cc);
    const float lo = x0f - A.x;
    const float hi = lo + 127.0f;
    float dxs = Bv * (-0.5f * fast_rcp(A.z));
    dxs = fminf(fmaxf(dxs, lo), hi);
    const float q = fmaf(fmaf(A.z, dxs, Bv), dxs, cc);
    mask = __ballot(q > QCUT);
  }

  // ---- main loop: surviving gaussians of this segment, ascending order ----
  float T0 = 1.f, T1 = 1.f;
  float r0 = 0.f, g0 = 0.f, b0 = 0.f, r1 = 0.f, g1 = 0.f, b1 = 0.f;
  while (mask) {
    const int bit = __ffsll(mask) - 1;
    mask &= mask - 1;
    const int g = seg * SEGLEN + bit;                  // wave-uniform -> LDS broadcast
    const float4 P = rowp[g];                          // {mx, ka, B, cc}
    const float4 C = colp[g];
    const float dx0 = px0 - P.x;
    const float dx1 = dx0 + 64.0f;
    const float m0 = fmaf(fmaf(P.y, dx0, P.z), dx0, P.w);
    const float m1 = fmaf(fmaf(P.y, dx1, P.z), dx1, P.w);
    const float a0 = fast_exp2(m0);
    const float a1 = fast_exp2(m1);
    const float aw0 = a0 * T0;
    const float aw1 = a1 * T1;
    r0 = fmaf(aw0, C.x, r0); g0 = fmaf(aw0, C.y, g0); b0 = fmaf(aw0, C.z, b0);
    r1 = fmaf(aw1, C.x, r1); g1 = fmaf(aw1, C.y, g1); b1 = fmaf(aw1, C.z, b1);
    T0 *= (1.0000001f - a0);                           // (1 - alpha + 1e-7)
    T1 *= (1.0000001f - a1);
  }

  part[seg][lane]      = make_float4(r0, g0, b0, T0);
  part[seg][lane + 64] = make_float4(r1, g1, b1, T1);
  __syncthreads();

  // ---- epilogue: sequential combine of the 8 segment partials per pixel ----
  if (tid < PXB) {
    float T = 1.f, R = 0.f, G = 0.f, B = 0.f;
#pragma unroll
    for (int s = 0; s < NSEG; ++s) {
      const float4 p = part[s][tid];
      R = fmaf(T, p.x, R);
      G = fmaf(T, p.y, G);
      B = fmaf(T, p.z, B);
      T *= p.w;
    }
    outstage[tid*3+0] = R;
    outstage[tid*3+1] = G;
    outstage[tid*3+2] = B;
  }
  __syncthreads();

  // coalesced fp32 store: 384 contiguous floats per block
  if (tid < PXB * 3) {
    out[pixbase * 3 + tid] = outstage[tid];
  }
}

extern "C" void kernel_launch(void* const* d_in, const int* in_sizes, int n_in,
                              void* d_out, int out_size, void* d_ws, size_t ws_size,
                              hipStream_t stream) {
  const float* means = (const float*)d_in[0];   // (512,2)
  const float* cov   = (const float*)d_in[1];   // (512,2,2)
  const float* opac  = (const float*)d_in[2];   // (512,)
  const float* cols  = (const float*)d_in[3];   // (512,3)
  float* out = (float*)d_out;                   // (256,256,3) float32
  float4* ws = (float4*)d_ws;                   // 24 KB used
  (void)in_sizes; (void)n_in; (void)out_size; (void)ws_size;
  prep_kernel<<<dim3(1), dim3(NG), 0, stream>>>(means, cov, opac, cols, ws);
  render_kernel<<<dim3(256 * 256 / PXB), dim3(512), 0, stream>>>(ws, out);
}

// Round 4
// 64.657 us; speedup vs baseline: 1.0224x; 1.0224x over previous
//
#include <hip/hip_runtime.h>

#ifndef __has_builtin
#define __has_builtin(x) 0
#endif

__device__ __forceinline__ float fast_exp2(float x) {
#if __has_builtin(__builtin_amdgcn_exp2f)
  return __builtin_amdgcn_exp2f(x);
#else
  return exp2f(x);
#endif
}
__device__ __forceinline__ float fast_rcp(float x) {
#if __has_builtin(__builtin_amdgcn_rcpf)
  return __builtin_amdgcn_rcpf(x);
#else
  return 1.0f / x;
#endif
}

#define NG     512
#define NSEG   8
#define SEGLEN 64          // gaussians per segment (one wave per segment)
#define PXB    128         // pixels per block = half an image row (constant y!)
#define QCUT   -21.0f      // exp2 exponent cutoff: alpha < 2^-21 ~ 4.8e-7 skipped

// Single fused kernel (one graph node): per-block inline preprocess (latency-
// overlapped, ~free) + per-wave cull with row-fold + culled main loop +
// associative 8-segment combine. Block: 512 threads = 8 waves; wave s owns
// gaussians [64s,64s+64); lane l owns pixels (base+l) and (base+l+64).
__global__ __launch_bounds__(512, 4) void render_kernel(
    const float* __restrict__ means, const float* __restrict__ cov,
    const float* __restrict__ opac,  const float* __restrict__ cols,
    float* __restrict__ out)
{
  __shared__ float4 arrA[NG];          // 8 KB {mx,my,ka,kb}
  __shared__ float2 arrB[NG];          // 4 KB {kc,ko}
  __shared__ float4 colp[NG];          // 8 KB {cr,cg,cb,-}
  __shared__ float4 rowp[NG];          // 8 KB row-folded {mx,ka,B,cc} (built in cull)
  __shared__ float4 part[NSEG][PXB];   // 16 KB per-segment per-pixel partials
  __shared__ float  outstage[PXB * 3]; // 1.5 KB staged coalesced store

  const int tid = threadIdx.x;

  // ---- inline preprocess: one gaussian per thread ----
  // exp2-space fold: alpha = exp2(ka*dx^2 + kb*dx*dy + kc*dy^2 + ko)
  {
    const int g = tid;
    const float mx = means[2*g], my = means[2*g+1];
    const float a = cov[4*g+0], b = cov[4*g+1], c = cov[4*g+2], d = cov[4*g+3];
    const float inv = 1.0f / (a*d - b*c);          // cov is PD, det >= 0.09
    const float HL2E = 0.72134752f;                // 0.5*log2(e)
    const float ka = -HL2E * d * inv;
    const float kb =  HL2E * (b + c) * inv;
    const float kc = -HL2E * a * inv;
    const float ko = log2f(opac[g]);               // opac in (0,1)
    arrA[g] = make_float4(mx, my, ka, kb);
    arrB[g] = make_float2(kc, ko);
    colp[g] = make_float4(cols[3*g+0], cols[3*g+1], cols[3*g+2], 0.f);
  }
  __syncthreads();

  const int lane = tid & 63;
  const int seg  = tid >> 6;
  const int pixbase = blockIdx.x * PXB;
  const float py  = (float)(pixbase >> 8) + 0.5f;      // block-constant row
  const float x0f = (float)(pixbase & 255) + 0.5f;     // x of local pixel 0
  const float px0 = x0f + (float)lane;                 // lane's first pixel x

  // ---- per-wave cull + row-fold: lane l handles gaussian seg*64+l ----
  // q(dx) = ka*dx^2 + B*dx + cc is concave (ka<0): max at clamp(-B/(2ka), lo, hi).
  // Side effect: rowp[g] = {mx, ka, B, cc} for this block's row (same-wave RAW:
  // wave s's main loop reads only entries wave s wrote -> no barrier needed).
  unsigned long long mask;
  {
    const int gt = seg * SEGLEN + lane;
    const float4 A  = arrA[gt];
    const float2 Bq = arrB[gt];
    const float dy = py - A.y;
    const float Bv = A.w * dy;                         // kb*dy
    const float cc = fmaf(Bq.x * dy, dy, Bq.y);        // kc*dy^2 + ko
    rowp[gt] = make_float4(A.x, A.z, Bv, cc);
    const float lo = x0f - A.x;
    const float hi = lo + 127.0f;
    float dxs = Bv * (-0.5f * fast_rcp(A.z));
    dxs = fminf(fmaxf(dxs, lo), hi);
    const float q = fmaf(fmaf(A.z, dxs, Bv), dxs, cc);
    mask = __ballot(q > QCUT);
  }

  // ---- main loop: surviving gaussians of this segment, ascending order ----
  float T0 = 1.f, T1 = 1.f;
  float r0 = 0.f, g0 = 0.f, b0 = 0.f, r1 = 0.f, g1 = 0.f, b1 = 0.f;
  while (mask) {
    const int bit = __ffsll(mask) - 1;
    mask &= mask - 1;
    const int g = seg * SEGLEN + bit;                  // wave-uniform -> LDS broadcast
    const float4 P = rowp[g];                          // {mx, ka, B, cc}
    const float4 C = colp[g];
    const float dx0 = px0 - P.x;
    const float dx1 = dx0 + 64.0f;
    const float m0 = fmaf(fmaf(P.y, dx0, P.z), dx0, P.w);
    const float m1 = fmaf(fmaf(P.y, dx1, P.z), dx1, P.w);
    const float a0 = fast_exp2(m0);
    const float a1 = fast_exp2(m1);
    const float aw0 = a0 * T0;
    const float aw1 = a1 * T1;
    r0 = fmaf(aw0, C.x, r0); g0 = fmaf(aw0, C.y, g0); b0 = fmaf(aw0, C.z, b0);
    r1 = fmaf(aw1, C.x, r1); g1 = fmaf(aw1, C.y, g1); b1 = fmaf(aw1, C.z, b1);
    T0 *= (1.0000001f - a0);                           // (1 - alpha + 1e-7)
    T1 *= (1.0000001f - a1);
  }

  part[seg][lane]      = make_float4(r0, g0, b0, T0);
  part[seg][lane + 64] = make_float4(r1, g1, b1, T1);
  __syncthreads();

  // ---- epilogue: sequential combine of the 8 segment partials per pixel ----
  if (tid < PXB) {
    float T = 1.f, R = 0.f, G = 0.f, B = 0.f;
#pragma unroll
    for (int s = 0; s < NSEG; ++s) {
      const float4 p = part[s][tid];
      R = fmaf(T, p.x, R);
      G = fmaf(T, p.y, G);
      B = fmaf(T, p.z, B);
      T *= p.w;
    }
    outstage[tid*3+0] = R;
    outstage[tid*3+1] = G;
    outstage[tid*3+2] = B;
  }
  __syncthreads();

  // coalesced fp32 store: 384 contiguous floats per block
  if (tid < PXB * 3) {
    out[pixbase * 3 + tid] = outstage[tid];
  }
}

extern "C" void kernel_launch(void* const* d_in, const int* in_sizes, int n_in,
                              void* d_out, int out_size, void* d_ws, size_t ws_size,
                              hipStream_t stream) {
  const float* means = (const float*)d_in[0];   // (512,2)
  const float* cov   = (const float*)d_in[1];   // (512,2,2)
  const float* opac  = (const float*)d_in[2];   // (512,)
  const float* cols  = (const float*)d_in[3];   // (512,3)
  float* out = (float*)d_out;                   // (256,256,3) float32
  (void)in_sizes; (void)n_in; (void)out_size; (void)d_ws; (void)ws_size;
  render_kernel<<<dim3(256 * 256 / PXB), dim3(512), 0, stream>>>(
      means, cov, opac, cols, out);
}